// Round 4
// baseline (196.829 us; speedup 1.0000x reference)
//
#include <hip/hip_runtime.h>

// LinearTextEmbedding: out[o] = (|bits[o & 4095]| > 0.5) ? 1 : 0 for the whole
// 48x1024x1024 float32 output (channel stride & image size are multiples of 4096).
// Write-bandwidth bound: 201.3 MB stores, 16 KB reads.
//
// R0: 1 float4/thread, 49152 blocks  -> kernel ~67 us (~3.0 TB/s)
// R1: 24 stores/thread, 2048 blocks  -> kernel ~75 us (~2.7 TB/s)  [regression]
// Harness poison fill hits 6.6 TB/s on this same buffer -> 2x headroom.
// R2/R3: nontemporal stores (bypass L2 dirty-line churn) + contiguous 16 KB
// per block. R2 failed to compile: __builtin_nontemporal_store needs a native
// clang vector type, not HIP_vector_type -> use ext_vector_type(4) float.

typedef float v4f __attribute__((ext_vector_type(4)));

#define N4    12582912u          // 48*1024*1024/4 float4 elements
#define BLK4  1024u              // float4 elements per block (16 KB)
#define NBLK  (N4 / BLK4)        // 12288 blocks

__device__ __forceinline__ v4f bin4(v4f b) {
    v4f v;
    v.x = (fabsf(b.x) > 0.5f) ? 1.0f : 0.0f;
    v.y = (fabsf(b.y) > 0.5f) ? 1.0f : 0.0f;
    v.z = (fabsf(b.z) > 0.5f) ? 1.0f : 0.0f;
    v.w = (fabsf(b.w) > 0.5f) ? 1.0f : 0.0f;
    return v;
}

__global__ __launch_bounds__(256) void
LinearTextEmbedding_57604101374655_kernel(const v4f* __restrict__ bits4,
                                          v4f* __restrict__ out) {
    unsigned tid  = threadIdx.x;
    unsigned base = blockIdx.x * BLK4 + tid;
    // Block base is a multiple of 1024, so the bits float4 index for store slot
    // (i*256 + tid) is just i*256 + tid. 16 KB input is L1-resident.
    v4f v0 = bin4(bits4[tid]);
    v4f v1 = bin4(bits4[256u + tid]);
    v4f v2 = bin4(bits4[512u + tid]);
    v4f v3 = bin4(bits4[768u + tid]);
    __builtin_nontemporal_store(v0, &out[base]);
    __builtin_nontemporal_store(v1, &out[base + 256u]);
    __builtin_nontemporal_store(v2, &out[base + 512u]);
    __builtin_nontemporal_store(v3, &out[base + 768u]);
}

extern "C" void kernel_launch(void* const* d_in, const int* in_sizes, int n_in,
                              void* d_out, int out_size, void* d_ws, size_t ws_size,
                              hipStream_t stream) {
    const v4f* bits4 = (const v4f*)d_in[0];
    v4f* out = (v4f*)d_out;
    LinearTextEmbedding_57604101374655_kernel<<<NBLK, 256, 0, stream>>>(bits4, out);
}